// Round 4
// baseline (486.397 us; speedup 1.0000x reference)
//
#include <hip/hip_runtime.h>
#include <hip/hip_bf16.h>

#define N_NODES 50000
#define N_EDGES 800000

static __device__ __forceinline__ float readlane_f(float v, int lane) {
    return __int_as_float(__builtin_amdgcn_readlane(__float_as_int(v), lane));
}

// ---------------------------------------------------------------------------
// row_ptr[i] = lower_bound(src, i); src is sorted. row_ptr[N] = E.
// ---------------------------------------------------------------------------
__global__ __launch_bounds__(256) void rowptr_kernel(const int* __restrict__ src,
                                                     int* __restrict__ row_ptr,
                                                     int n, int e) {
    int i = blockIdx.x * 256 + threadIdx.x;
    if (i > n) return;
    int lo = 0, hi = e;
    while (lo < hi) {
        int mid = (lo + hi) >> 1;
        if (src[mid] < i) lo = mid + 1; else hi = mid;
    }
    row_ptr[i] = lo;
}

// ---------------------------------------------------------------------------
// Fold duplicated head-0/1 input columns of lin1_w / lin2_w (64 x 256) into
// planar K=192 weights matching agg's output layout [i, c*64 + f].
// ---------------------------------------------------------------------------
__global__ __launch_bounds__(256) void wprep_kernel(const float* __restrict__ lw1,
                                                    const float* __restrict__ lw2,
                                                    float* __restrict__ w1p,
                                                    float* __restrict__ w2p) {
    int idx = blockIdx.x * 256 + threadIdx.x;
    if (idx >= 64 * 192) return;
    int o = idx / 192, r = idx % 192;
    int c = r >> 6, f = r & 63;
    const float* lw = (blockIdx.y == 0) ? lw1 : lw2;
    float v;
    if (c == 0)      v = lw[o * 256 + f * 4 + 0] + lw[o * 256 + f * 4 + 1];
    else if (c == 1) v = lw[o * 256 + f * 4 + 2];
    else             v = lw[o * 256 + f * 4 + 3];
    (blockIdx.y == 0 ? w1p : w2p)[idx] = v;
}

// ---------------------------------------------------------------------------
// lin: h[i,o] = leaky_relu(x[i,:].w[o,:] + b[o]), o in [0,64).
// lane = output column o. Each wave owns 16 rows (block of 4 waves = 64 rows).
// w (64xK) staged ONCE into LDS with +2 row padding (2-way bank conflicts =
// free); per k16-step each lane holds w[o][k0..k0+15] in regs (8x ds_read_b64)
// and x row values are wave-uniform loads (scalar path) -> 256 FMA / step.
// No barriers in the main loop. Fused score epilogue via 64-lane butterfly.
// ---------------------------------------------------------------------------
template <int K>
__global__ __launch_bounds__(256) void lin_kernel(const float* __restrict__ in,
                                                  const float* __restrict__ w,
                                                  const float* __restrict__ b,
                                                  const float* __restrict__ aw,
                                                  float* __restrict__ h,
                                                  float2* __restrict__ s, int n) {
    __shared__ float wlds[64 * (K + 2)];
    const int t = threadIdx.x;
    const int lane = t & 63;

    // stage w (row-major 64xK) -> wlds[o*(K+2)+k], float2 granularity
    const float2* w2 = (const float2*)w;
    for (int p = t; p < 64 * K / 2; p += 256) {
        int o = p / (K / 2);
        int kk = (p - o * (K / 2)) * 2;
        *(float2*)&wlds[o * (K + 2) + kk] = w2[p];
    }
    __syncthreads();

    const int wid = __builtin_amdgcn_readfirstlane(t >> 6);
    const int i0 = blockIdx.x * 64 + wid * 16;

    float acc[16];
    #pragma unroll
    for (int r = 0; r < 16; ++r) acc[r] = 0.f;

    for (int k0 = 0; k0 < K; k0 += 16) {
        float2 wr[8];
        #pragma unroll
        for (int q = 0; q < 8; ++q)
            wr[q] = *(const float2*)&wlds[lane * (K + 2) + k0 + 2 * q];
        #pragma unroll
        for (int r = 0; r < 16; ++r) {
            int row = i0 + r;
            row = row < n - 1 ? row : n - 1;  // clamp: stores are guarded later
            const float4* xr = (const float4*)(in + (long)row * K + k0);
            float4 a = xr[0], b4 = xr[1], c4 = xr[2], d4 = xr[3];
            acc[r] += a.x * wr[0].x + a.y * wr[0].y + a.z * wr[1].x + a.w * wr[1].y
                    + b4.x * wr[2].x + b4.y * wr[2].y + b4.z * wr[3].x + b4.w * wr[3].y
                    + c4.x * wr[4].x + c4.y * wr[4].y + c4.z * wr[5].x + c4.w * wr[5].y
                    + d4.x * wr[6].x + d4.y * wr[6].y + d4.z * wr[7].x + d4.w * wr[7].y;
        }
    }

    const float bias = b[lane];
    const float a2c = aw[2 * 128 + lane] + aw[2 * 128 + 64 + lane];
    const float a3c = aw[3 * 128 + lane] + aw[3 * 128 + 64 + lane];

    #pragma unroll
    for (int r = 0; r < 16; ++r) {
        int row = i0 + r;
        if (row < n) {
            float v = acc[r] + bias;
            v = v > 0.f ? v : 0.2f * v;
            h[(long)row * 64 + lane] = v;
            float q2 = v * a2c, q3 = v * a3c;
            #pragma unroll
            for (int o = 1; o < 64; o <<= 1) {
                q2 += __shfl_xor(q2, o);
                q3 += __shfl_xor(q3, o);
            }
            if (lane == 0) s[row] = make_float2(q2, q3);
        }
    }
}

// ---------------------------------------------------------------------------
// Wave-per-node aggregation, lane = feature. 3 accumulators per lane:
// mean (heads 0,1: uniform alpha), alpha2-, alpha3-weighted sums.
// Phase B unrolled x8: 8 independent row loads in flight per iteration.
// ---------------------------------------------------------------------------
__global__ __launch_bounds__(256) void agg_kernel(const float* __restrict__ hfeat,
                                                  const float2* __restrict__ s,
                                                  const int* __restrict__ dst,
                                                  const int* __restrict__ row_ptr,
                                                  float* __restrict__ out,
                                                  int final_layer, int n) {
    const int t = threadIdx.x;
    const int l = t & 63;
    const int i = blockIdx.x * 4 + (t >> 6);
    if (i >= n) return;
    const int r0 = row_ptr[i], r1 = row_ptr[i + 1];
    const int deg = r1 - r0;

    if (deg == 0) {
        if (!final_layer) {
            out[(long)i * 192 + l] = 0.f;
            out[(long)i * 192 + 64 + l] = 0.f;
            out[(long)i * 192 + 128 + l] = 0.f;
        } else {
            out[(long)i * 64 + l] = 0.f;
        }
        return;
    }

    const float inv_deg = 1.f / (float)deg;
    float accm = 0.f, acc2 = 0.f, acc3 = 0.f;

    if (deg <= 64) {
        // ---- phase A: lane-parallel softmax over edges (heads 2,3) ----
        int dl = 0;
        float g2 = -INFINITY, g3 = -INFINITY;
        if (l < deg) {
            dl = dst[r0 + l];
            float2 sv = s[dl];
            g2 = sv.x; g3 = sv.y;
        }
        float m2 = g2, m3 = g3;
        #pragma unroll
        for (int o = 1; o < 64; o <<= 1) {
            m2 = fmaxf(m2, __shfl_xor(m2, o));
            m3 = fmaxf(m3, __shfl_xor(m3, o));
        }
        float p2 = (l < deg) ? __expf(g2 - m2) : 0.f;
        float p3 = (l < deg) ? __expf(g3 - m3) : 0.f;
        float S2 = p2, S3 = p3;
        #pragma unroll
        for (int o = 1; o < 64; o <<= 1) { S2 += __shfl_xor(S2, o); S3 += __shfl_xor(S3, o); }
        float a2 = p2 / S2, a3 = p3 / S3;

        // ---- phase B: unroll x8, 8 loads in flight ----
        int jj = 0;
        for (; jj + 8 <= deg; jj += 8) {
            int d[8];
            float hv[8], w2v[8], w3v[8];
            #pragma unroll
            for (int q = 0; q < 8; ++q) d[q] = __builtin_amdgcn_readlane(dl, jj + q);
            #pragma unroll
            for (int q = 0; q < 8; ++q) hv[q] = hfeat[(long)d[q] * 64 + l];
            #pragma unroll
            for (int q = 0; q < 8; ++q) {
                w2v[q] = readlane_f(a2, jj + q);
                w3v[q] = readlane_f(a3, jj + q);
            }
            #pragma unroll
            for (int q = 0; q < 8; ++q) {
                accm += hv[q];
                acc2 += w2v[q] * hv[q];
                acc3 += w3v[q] * hv[q];
            }
        }
        for (; jj < deg; ++jj) {
            int d = __builtin_amdgcn_readlane(dl, jj);
            float w2 = readlane_f(a2, jj);
            float w3 = readlane_f(a3, jj);
            float hv = hfeat[(long)d * 64 + l];
            accm += hv;
            acc2 += w2 * hv;
            acc3 += w3 * hv;
        }
    } else {
        // ---- generic fallback (deg > 64), essentially never for this graph ----
        float m2 = -INFINITY, m3 = -INFINITY;
        for (int e = r0 + l; e < r1; e += 64) {
            float2 sv = s[dst[e]];
            m2 = fmaxf(m2, sv.x); m3 = fmaxf(m3, sv.y);
        }
        #pragma unroll
        for (int o = 1; o < 64; o <<= 1) {
            m2 = fmaxf(m2, __shfl_xor(m2, o));
            m3 = fmaxf(m3, __shfl_xor(m3, o));
        }
        float S2 = 0.f, S3 = 0.f;
        for (int e = r0 + l; e < r1; e += 64) {
            float2 sv = s[dst[e]];
            S2 += __expf(sv.x - m2); S3 += __expf(sv.y - m3);
        }
        #pragma unroll
        for (int o = 1; o < 64; o <<= 1) { S2 += __shfl_xor(S2, o); S3 += __shfl_xor(S3, o); }
        const float i2 = 1.f / S2, i3 = 1.f / S3;

        for (int c0 = r0; c0 < r1; c0 += 64) {
            const int cn = min(64, r1 - c0);
            int dl = 0;
            float w2l = 0.f, w3l = 0.f;
            if (l < cn) {
                dl = dst[c0 + l];
                float2 sv = s[dl];
                w2l = __expf(sv.x - m2) * i2;
                w3l = __expf(sv.y - m3) * i3;
            }
            for (int j = 0; j < cn; ++j) {
                int d = __builtin_amdgcn_readlane(dl, j);
                float w2 = readlane_f(w2l, j);
                float w3 = readlane_f(w3l, j);
                float hv = hfeat[(long)d * 64 + l];
                accm += hv;
                acc2 += w2 * hv;
                acc3 += w3 * hv;
            }
        }
    }

    if (!final_layer) {
        out[(long)i * 192 + l]       = fmaxf(accm * inv_deg, 0.f);
        out[(long)i * 192 + 64 + l]  = fmaxf(acc2, 0.f);
        out[(long)i * 192 + 128 + l] = fmaxf(acc3, 0.f);
    } else {
        out[(long)i * 64 + l] = fmaxf(0.5f * inv_deg * accm + 0.25f * (acc2 + acc3), 0.f);
    }
}

// ---------------------------------------------------------------------------
extern "C" void kernel_launch(void* const* d_in, const int* in_sizes, int n_in,
                              void* d_out, int out_size, void* d_ws, size_t ws_size,
                              hipStream_t stream) {
    const float* x = (const float*)d_in[0];
    const float* lw[3] = {(const float*)d_in[1], (const float*)d_in[5], (const float*)d_in[9]};
    const float* lb[3] = {(const float*)d_in[2], (const float*)d_in[6], (const float*)d_in[10]};
    const float* aw[3] = {(const float*)d_in[3], (const float*)d_in[7], (const float*)d_in[11]};
    const int* src = (const int*)d_in[13];
    const int* dst = (const int*)d_in[14];
    float* out = (float*)d_out;

    const int N = N_NODES, E = N_EDGES;

    // ws layout (floats): bufA[N*192] | h[N*64] | s[N*2] | w1p[64*192] | w2p[64*192] | row_ptr[N+1]
    float* bufA = (float*)d_ws;
    float* hbuf = bufA + (size_t)N * 192;
    float2* sbuf = (float2*)(hbuf + (size_t)N * 64);
    float* w1p = (float*)(sbuf + N);
    float* w2p = w1p + 64 * 192;
    int* row_ptr = (int*)(w2p + 64 * 192);

    rowptr_kernel<<<(N + 1 + 255) / 256, 256, 0, stream>>>(src, row_ptr, N, E);
    wprep_kernel<<<dim3(48, 2), 256, 0, stream>>>(lw[1], lw[2], w1p, w2p);

    const int lin_grid = (N + 63) / 64;
    const int agg_grid = (N + 3) / 4;

    // ---- layer 0 ----
    lin_kernel<128><<<lin_grid, 256, 0, stream>>>(x, lw[0], lb[0], aw[0], hbuf, sbuf, N);
    agg_kernel<<<agg_grid, 256, 0, stream>>>(hbuf, sbuf, dst, row_ptr, bufA, 0, N);

    // ---- layer 1 ----
    lin_kernel<192><<<lin_grid, 256, 0, stream>>>(bufA, w1p, lb[1], aw[1], hbuf, sbuf, N);
    agg_kernel<<<agg_grid, 256, 0, stream>>>(hbuf, sbuf, dst, row_ptr, bufA, 0, N);

    // ---- layer 2 (final) ----
    lin_kernel<192><<<lin_grid, 256, 0, stream>>>(bufA, w2p, lb[2], aw[2], hbuf, sbuf, N);
    agg_kernel<<<agg_grid, 256, 0, stream>>>(hbuf, sbuf, dst, row_ptr, out, 1, N);
}

// Round 5
// 317.431 us; speedup vs baseline: 1.5323x; 1.5323x over previous
//
#include <hip/hip_runtime.h>
#include <hip/hip_bf16.h>

#define N_NODES 50000
#define N_EDGES 800000

static __device__ __forceinline__ float readlane_f(float v, int lane) {
    return __int_as_float(__builtin_amdgcn_readlane(__float_as_int(v), lane));
}

// ---------------------------------------------------------------------------
// row_ptr[i] = lower_bound(src, i); src is sorted. row_ptr[N] = E.
// ---------------------------------------------------------------------------
__global__ __launch_bounds__(256) void rowptr_kernel(const int* __restrict__ src,
                                                     int* __restrict__ row_ptr,
                                                     int n, int e) {
    int i = blockIdx.x * 256 + threadIdx.x;
    if (i > n) return;
    int lo = 0, hi = e;
    while (lo < hi) {
        int mid = (lo + hi) >> 1;
        if (src[mid] < i) lo = mid + 1; else hi = mid;
    }
    row_ptr[i] = lo;
}

// ---------------------------------------------------------------------------
// Fold duplicated head-0/1 input columns of lin1_w / lin2_w (64 x 256) into
// planar K=192 weights matching agg's output layout [i, c*64 + f].
// ---------------------------------------------------------------------------
__global__ __launch_bounds__(256) void wprep_kernel(const float* __restrict__ lw1,
                                                    const float* __restrict__ lw2,
                                                    float* __restrict__ w1p,
                                                    float* __restrict__ w2p) {
    int idx = blockIdx.x * 256 + threadIdx.x;
    if (idx >= 64 * 192) return;
    int o = idx / 192, r = idx % 192;
    int c = r >> 6, f = r & 63;
    const float* lw = (blockIdx.y == 0) ? lw1 : lw2;
    float v;
    if (c == 0)      v = lw[o * 256 + f * 4 + 0] + lw[o * 256 + f * 4 + 1];
    else if (c == 1) v = lw[o * 256 + f * 4 + 2];
    else             v = lw[o * 256 + f * 4 + 3];
    (blockIdx.y == 0 ? w1p : w2p)[idx] = v;
}

// ---------------------------------------------------------------------------
// lin: h[i,o] = leaky_relu(x[i,:].w[o,:] + b[o]), o in [0,64).
// 128 threads (2 waves), 128x64 output tile, 8x8 per-thread register tile,
// BK=16 LDS staging ([kk][row] layout; fragment reads are 16B, 2-way banked
// = free). 4 ds_read_b128 per 64 FMA -> ~105 TF LDS-bound ceiling.
// Fused score epilogue: 8-lane partial-dot reduce (xor 1,2,4).
// ---------------------------------------------------------------------------
template <int K>
__global__ __launch_bounds__(128) void lin_kernel(const float* __restrict__ in,
                                                  const float* __restrict__ w,
                                                  const float* __restrict__ b,
                                                  const float* __restrict__ aw,
                                                  float* __restrict__ h,
                                                  float2* __restrict__ s, int n) {
    __shared__ float xs[16][128];
    __shared__ float ws[16][64];
    const int t = threadIdx.x;          // 0..127
    const int tx = t & 7;               // col group: cols tx*8 .. tx*8+7
    const int ty = t >> 3;              // row group: rows ty*8 .. ty*8+7
    const long i0 = (long)blockIdx.x * 128;

    float acc[8][8] = {};

    for (int k0 = 0; k0 < K; k0 += 16) {
        __syncthreads();  // protect previous iteration's fragment reads
        #pragma unroll
        for (int q = 0; q < 4; ++q) {
            int p = t + 128 * q;            // 0..511
            int row = p >> 2, kq = p & 3;
            long rr = i0 + row; if (rr >= n) rr = n - 1;
            float4 v = *(const float4*)(in + rr * K + k0 + kq * 4);
            xs[kq * 4 + 0][row] = v.x; xs[kq * 4 + 1][row] = v.y;
            xs[kq * 4 + 2][row] = v.z; xs[kq * 4 + 3][row] = v.w;
        }
        #pragma unroll
        for (int q = 0; q < 2; ++q) {
            int p = t + 128 * q;            // 0..255
            int o = p >> 2, kq = p & 3;
            float4 v = *(const float4*)(w + o * K + k0 + kq * 4);
            ws[kq * 4 + 0][o] = v.x; ws[kq * 4 + 1][o] = v.y;
            ws[kq * 4 + 2][o] = v.z; ws[kq * 4 + 3][o] = v.w;
        }
        __syncthreads();
        #pragma unroll
        for (int kk = 0; kk < 16; ++kk) {
            float4 a0 = *(const float4*)&xs[kk][ty * 8];
            float4 a1 = *(const float4*)&xs[kk][ty * 8 + 4];
            float4 b0 = *(const float4*)&ws[kk][tx * 8];
            float4 b1 = *(const float4*)&ws[kk][tx * 8 + 4];
            float av[8] = {a0.x, a0.y, a0.z, a0.w, a1.x, a1.y, a1.z, a1.w};
            float bv[8] = {b0.x, b0.y, b0.z, b0.w, b1.x, b1.y, b1.z, b1.w};
            #pragma unroll
            for (int r = 0; r < 8; ++r)
                #pragma unroll
                for (int c = 0; c < 8; ++c)
                    acc[r][c] += av[r] * bv[c];
        }
    }

    // epilogue: bias + leaky relu + store + fused score
    float bias[8], a2c[8], a3c[8];
    #pragma unroll
    for (int c = 0; c < 8; ++c) {
        int col = tx * 8 + c;
        bias[c] = b[col];
        a2c[c] = aw[2 * 128 + col] + aw[2 * 128 + 64 + col];
        a3c[c] = aw[3 * 128 + col] + aw[3 * 128 + 64 + col];
    }
    #pragma unroll
    for (int r = 0; r < 8; ++r) {
        long row = i0 + ty * 8 + r;
        if (row >= n) break;
        float v[8];
        float q2 = 0.f, q3 = 0.f;
        #pragma unroll
        for (int c = 0; c < 8; ++c) {
            float u = acc[r][c] + bias[c];
            u = u > 0.f ? u : 0.2f * u;
            v[c] = u;
            q2 += u * a2c[c];
            q3 += u * a3c[c];
        }
        *(float4*)(h + row * 64 + tx * 8)     = make_float4(v[0], v[1], v[2], v[3]);
        *(float4*)(h + row * 64 + tx * 8 + 4) = make_float4(v[4], v[5], v[6], v[7]);
        // reduce across the 8 threads (consecutive lanes) sharing this row
        #pragma unroll
        for (int o = 1; o < 8; o <<= 1) {
            q2 += __shfl_xor(q2, o);
            q3 += __shfl_xor(q3, o);
        }
        if (tx == 0) s[row] = make_float2(q2, q3);
    }
}

// ---------------------------------------------------------------------------
// Wave-per-node aggregation, lane = feature. 3 accumulators per lane:
// mean (heads 0,1: uniform alpha), alpha2-, alpha3-weighted sums.
// Phase B: masked 8-blocks — ceil(deg/8) iterations, 8 loads in flight,
// no serial tail (invalid slots: clamped index, zero weight).
// ---------------------------------------------------------------------------
__global__ __launch_bounds__(256) void agg_kernel(const float* __restrict__ hfeat,
                                                  const float2* __restrict__ s,
                                                  const int* __restrict__ dst,
                                                  const int* __restrict__ row_ptr,
                                                  float* __restrict__ out,
                                                  int final_layer, int n) {
    const int t = threadIdx.x;
    const int l = t & 63;
    const int i = blockIdx.x * 4 + (t >> 6);
    if (i >= n) return;
    const int r0 = row_ptr[i], r1 = row_ptr[i + 1];
    const int deg = r1 - r0;

    if (deg == 0) {
        if (!final_layer) {
            out[(long)i * 192 + l] = 0.f;
            out[(long)i * 192 + 64 + l] = 0.f;
            out[(long)i * 192 + 128 + l] = 0.f;
        } else {
            out[(long)i * 64 + l] = 0.f;
        }
        return;
    }

    const float inv_deg = 1.f / (float)deg;
    float accm = 0.f, acc2 = 0.f, acc3 = 0.f;

    if (deg <= 64) {
        // ---- phase A: lane-parallel softmax over edges (heads 2,3) ----
        int dl = 0;
        float g2 = -INFINITY, g3 = -INFINITY;
        if (l < deg) {
            dl = dst[r0 + l];
            float2 sv = s[dl];
            g2 = sv.x; g3 = sv.y;
        }
        float m2 = g2, m3 = g3;
        #pragma unroll
        for (int o = 1; o < 64; o <<= 1) {
            m2 = fmaxf(m2, __shfl_xor(m2, o));
            m3 = fmaxf(m3, __shfl_xor(m3, o));
        }
        float p2 = (l < deg) ? __expf(g2 - m2) : 0.f;
        float p3 = (l < deg) ? __expf(g3 - m3) : 0.f;
        float S2 = p2, S3 = p3;
        #pragma unroll
        for (int o = 1; o < 64; o <<= 1) { S2 += __shfl_xor(S2, o); S3 += __shfl_xor(S3, o); }
        float a2 = p2 / S2, a3 = p3 / S3;

        // ---- phase B: masked 8-blocks, 8 loads in flight, no serial tail ----
        for (int jj = 0; jj < deg; jj += 8) {
            int d[8];
            float hv[8], wmv[8], w2v[8], w3v[8];
            #pragma unroll
            for (int q = 0; q < 8; ++q) {
                int e = jj + q;
                int ei = e < deg ? e : deg - 1;   // scalar-uniform clamp
                d[q] = __builtin_amdgcn_readlane(dl, ei);
            }
            #pragma unroll
            for (int q = 0; q < 8; ++q) hv[q] = hfeat[(long)d[q] * 64 + l];
            #pragma unroll
            for (int q = 0; q < 8; ++q) {
                int e = jj + q;
                int ei = e < deg ? e : deg - 1;
                float valid = e < deg ? 1.f : 0.f;
                wmv[q] = valid;
                w2v[q] = valid * readlane_f(a2, ei);
                w3v[q] = valid * readlane_f(a3, ei);
            }
            #pragma unroll
            for (int q = 0; q < 8; ++q) {
                accm += wmv[q] * hv[q];
                acc2 += w2v[q] * hv[q];
                acc3 += w3v[q] * hv[q];
            }
        }
    } else {
        // ---- generic fallback (deg > 64), essentially never for this graph ----
        float m2 = -INFINITY, m3 = -INFINITY;
        for (int e = r0 + l; e < r1; e += 64) {
            float2 sv = s[dst[e]];
            m2 = fmaxf(m2, sv.x); m3 = fmaxf(m3, sv.y);
        }
        #pragma unroll
        for (int o = 1; o < 64; o <<= 1) {
            m2 = fmaxf(m2, __shfl_xor(m2, o));
            m3 = fmaxf(m3, __shfl_xor(m3, o));
        }
        float S2 = 0.f, S3 = 0.f;
        for (int e = r0 + l; e < r1; e += 64) {
            float2 sv = s[dst[e]];
            S2 += __expf(sv.x - m2); S3 += __expf(sv.y - m3);
        }
        #pragma unroll
        for (int o = 1; o < 64; o <<= 1) { S2 += __shfl_xor(S2, o); S3 += __shfl_xor(S3, o); }
        const float i2 = 1.f / S2, i3 = 1.f / S3;

        for (int c0 = r0; c0 < r1; c0 += 64) {
            const int cn = min(64, r1 - c0);
            int dl = 0;
            float w2l = 0.f, w3l = 0.f;
            if (l < cn) {
                dl = dst[c0 + l];
                float2 sv = s[dl];
                w2l = __expf(sv.x - m2) * i2;
                w3l = __expf(sv.y - m3) * i3;
            }
            for (int jj = 0; jj < cn; jj += 8) {
                int d[8];
                float hv[8], wmv[8], w2v[8], w3v[8];
                #pragma unroll
                for (int q = 0; q < 8; ++q) {
                    int e = jj + q;
                    int ei = e < cn ? e : cn - 1;
                    d[q] = __builtin_amdgcn_readlane(dl, ei);
                }
                #pragma unroll
                for (int q = 0; q < 8; ++q) hv[q] = hfeat[(long)d[q] * 64 + l];
                #pragma unroll
                for (int q = 0; q < 8; ++q) {
                    int e = jj + q;
                    int ei = e < cn ? e : cn - 1;
                    float valid = e < cn ? 1.f : 0.f;
                    wmv[q] = valid;
                    w2v[q] = valid * readlane_f(w2l, ei);
                    w3v[q] = valid * readlane_f(w3l, ei);
                }
                #pragma unroll
                for (int q = 0; q < 8; ++q) {
                    accm += wmv[q] * hv[q];
                    acc2 += w2v[q] * hv[q];
                    acc3 += w3v[q] * hv[q];
                }
            }
        }
    }

    if (!final_layer) {
        out[(long)i * 192 + l]       = fmaxf(accm * inv_deg, 0.f);
        out[(long)i * 192 + 64 + l]  = fmaxf(acc2, 0.f);
        out[(long)i * 192 + 128 + l] = fmaxf(acc3, 0.f);
    } else {
        out[(long)i * 64 + l] = fmaxf(0.5f * inv_deg * accm + 0.25f * (acc2 + acc3), 0.f);
    }
}

// ---------------------------------------------------------------------------
extern "C" void kernel_launch(void* const* d_in, const int* in_sizes, int n_in,
                              void* d_out, int out_size, void* d_ws, size_t ws_size,
                              hipStream_t stream) {
    const float* x = (const float*)d_in[0];
    const float* lw[3] = {(const float*)d_in[1], (const float*)d_in[5], (const float*)d_in[9]};
    const float* lb[3] = {(const float*)d_in[2], (const float*)d_in[6], (const float*)d_in[10]};
    const float* aw[3] = {(const float*)d_in[3], (const float*)d_in[7], (const float*)d_in[11]};
    const int* src = (const int*)d_in[13];
    const int* dst = (const int*)d_in[14];
    float* out = (float*)d_out;

    const int N = N_NODES, E = N_EDGES;

    // ws layout (floats): bufA[N*192] | h[N*64] | s[N*2] | w1p[64*192] | w2p[64*192] | row_ptr[N+1]
    float* bufA = (float*)d_ws;
    float* hbuf = bufA + (size_t)N * 192;
    float2* sbuf = (float2*)(hbuf + (size_t)N * 64);
    float* w1p = (float*)(sbuf + N);
    float* w2p = w1p + 64 * 192;
    int* row_ptr = (int*)(w2p + 64 * 192);

    rowptr_kernel<<<(N + 1 + 255) / 256, 256, 0, stream>>>(src, row_ptr, N, E);
    wprep_kernel<<<dim3(48, 2), 256, 0, stream>>>(lw[1], lw[2], w1p, w2p);

    const int lin_grid = (N + 127) / 128;
    const int agg_grid = (N + 3) / 4;

    // ---- layer 0 ----
    lin_kernel<128><<<lin_grid, 128, 0, stream>>>(x, lw[0], lb[0], aw[0], hbuf, sbuf, N);
    agg_kernel<<<agg_grid, 256, 0, stream>>>(hbuf, sbuf, dst, row_ptr, bufA, 0, N);

    // ---- layer 1 ----
    lin_kernel<192><<<lin_grid, 128, 0, stream>>>(bufA, w1p, lb[1], aw[1], hbuf, sbuf, N);
    agg_kernel<<<agg_grid, 256, 0, stream>>>(hbuf, sbuf, dst, row_ptr, bufA, 0, N);

    // ---- layer 2 (final) ----
    lin_kernel<192><<<lin_grid, 128, 0, stream>>>(bufA, w2p, lb[2], aw[2], hbuf, sbuf, N);
    agg_kernel<<<agg_grid, 256, 0, stream>>>(hbuf, sbuf, dst, row_ptr, out, 1, N);
}